// Round 4
// baseline (1122.063 us; speedup 1.0000x reference)
//
#include <hip/hip_runtime.h>
#include <math.h>

#define HID 128
#define NLAYERS 4
#define NGRAPHS 200
#define NCLASSES 10
#define BN_EPS 1e-5f

typedef short bf16x8 __attribute__((ext_vector_type(8)));
typedef float f32x4 __attribute__((ext_vector_type(4)));
typedef float f32x2 __attribute__((ext_vector_type(2)));
typedef unsigned int u32x4 __attribute__((ext_vector_type(4)));

__device__ __forceinline__ ushort f2bf(float f) {
    unsigned u = __float_as_uint(f);
    u = (u + 0x7fffu + ((u >> 16) & 1u)) >> 16;
    return (ushort)u;
}
__device__ __forceinline__ float bf2f(unsigned us) { return __uint_as_float(us << 16); }

// ---------------- prep kernels ----------------

// A[:,128:256] = bf16(x)  (h state lives only in A's h-half, bf16)
__global__ void k_init_x(const float* __restrict__ x, ushort* __restrict__ A, int N) {
    int idx = blockIdx.x * blockDim.x + threadIdx.x;
    if (idx < N * HID) {
        int n = idx >> 7, c = idx & 127;
        A[n * 256 + 128 + c] = f2bf(x[idx]);
    }
}

// C[l][k][j] = sum_o W_l[k][o] * w_ih[j][o]; blocks 0..3 also fold the bias vector.
__global__ __launch_bounds__(128) void k_wgemm(const float* __restrict__ W,
                                               const float* __restrict__ w_ih,
                                               const float* __restrict__ b_ih,
                                               const float* __restrict__ b_hh,
                                               float* __restrict__ C,
                                               float* __restrict__ bias) {
    int l = blockIdx.x >> 7, k = blockIdx.x & 127;
    __shared__ float wrow[128];
    wrow[threadIdx.x] = W[(l << 14) + k * 128 + threadIdx.x];
    __syncthreads();
    for (int j = threadIdx.x; j < 384; j += 128) {
        float acc = 0.f;
#pragma unroll 4
        for (int o = 0; o < 128; ++o) acc += wrow[o] * w_ih[j * 128 + o];
        C[((size_t)l * 128 + k) * 384 + j] = acc;
    }
    if (blockIdx.x < 4) {
        int j = blockIdx.x * 128 + threadIdx.x; // 0..511
        float v;
        if (j < 256)      v = b_ih[j] + b_hh[j];
        else if (j < 384) v = b_ih[j];
        else              v = b_hh[j - 128];
        bias[j] = v;
    }
}

// Per-layer combined GRU weights in MFMA-fragment order (K=256 over [s|h], 512 outs)
__global__ void k_build_Bc(const float* __restrict__ C, const float* __restrict__ w_hh,
                           ushort* __restrict__ Bc2) {
    int idx = blockIdx.x * blockDim.x + threadIdx.x;
    if (idx >= NLAYERS * 512 * 256) return;
    int jf = idx & 7, lane = (idx >> 3) & 63, ks = (idx >> 9) & 7, ct = (idx >> 12) & 31;
    int l = idx >> 17;
    int o = ct * 16 + (lane & 15);
    int k = ks * 32 + (lane >> 4) * 8 + jf;
    float v;
    if (k < 128)      v = (o < 384) ? C[((size_t)l * 128 + k) * 384 + o] : 0.f;
    else if (o < 256) v = w_hh[o * 128 + (k - 128)];
    else if (o < 384) v = 0.f;
    else              v = w_hh[(o - 128) * 128 + (k - 128)];
    Bc2[idx] = f2bf(v);
}

// fc1_w[o][k] -> fragment order (K=128: ks in [0,4), ct in [0,8))
__global__ void k_cvt_fc1(const float* __restrict__ w, ushort* __restrict__ B2) {
    int idx = blockIdx.x * blockDim.x + threadIdx.x;
    if (idx >= 16384) return;
    int j = idx & 7, lane = (idx >> 3) & 63, ks = (idx >> 9) & 3, ct = idx >> 11;
    int o = ct * 16 + (lane & 15);
    int k = ks * 32 + (lane >> 4) * 8 + j;
    B2[idx] = f2bf(w[o * 128 + k]);
}

// ---------------- CSR build: staged counting-sort (no write amplification) ----------
// R10 lesson: NO dynamically-indexed register arrays (-> scratch). Scatter pass
// re-reads the chunk from global (L1/L2-hot after the hist pass).

#define CHUNK 2048

// blocks [0,nchunk): per-chunk bucket histogram; blocks [nchunk, ...): gstart
__global__ __launch_bounds__(256) void k_bhist(const int* __restrict__ ei, int E,
                                               int nb, int* __restrict__ bhist,
                                               const int* __restrict__ batch,
                                               int* __restrict__ gstart, int N,
                                               int nchunk) {
    if ((int)blockIdx.x < nchunk) {
        __shared__ int lh[256];
        int t = threadIdx.x;
        lh[t] = 0;
        __syncthreads();
        int base = blockIdx.x * CHUNK;
        int end = min(base + CHUNK, E);
        for (int i = base + t; i < end; i += 256) atomicAdd(&lh[ei[E + i] >> 9], 1);
        __syncthreads();
        if (t < nb && lh[t]) atomicAdd(&bhist[t], lh[t]);
    } else {
        int n = (blockIdx.x - nchunk) * 256 + threadIdx.x;
        if (n > N) return;
        int curb = (n == N) ? NGRAPHS : batch[n];
        int prev = (n == 0) ? -1 : batch[n - 1];
        for (int g = prev + 1; g <= curb; ++g) gstart[g] = n;
    }
}

__global__ void k_bscan(const int* __restrict__ bhist, int nb, int* __restrict__ bstart,
                        int* __restrict__ bcur, int E) {
    __shared__ int s[256];
    int t = threadIdx.x;
    int v = (t < nb) ? bhist[t] : 0;
    s[t] = v;
    __syncthreads();
    for (int off = 1; off < 256; off <<= 1) {
        int a = (t >= off) ? s[t - off] : 0;
        __syncthreads();
        s[t] += a;
        __syncthreads();
    }
    if (t < nb) { int ex = s[t] - v; bstart[t] = ex; bcur[t] = ex; }
    if (t == 0) bstart[nb] = E;
}

__global__ __launch_bounds__(256) void k_binfill(const int* __restrict__ ei, int E,
                                                 int nb, int* __restrict__ bcur,
                                                 int2* __restrict__ binned) {
    __shared__ int eh[256], eoff[256], ecur[256], gbase[256];
    __shared__ int2 sbuf[CHUNK];
    int t = threadIdx.x;
    eh[t] = 0; ecur[t] = 0;
    __syncthreads();
    int base = blockIdx.x * CHUNK;
    int cnt = min(CHUNK, E - base);
    for (int i = t; i < cnt; i += 256) atomicAdd(&eh[ei[E + base + i] >> 9], 1);
    __syncthreads();
    int v = eh[t];
    eoff[t] = v;
    __syncthreads();
    for (int off = 1; off < 256; off <<= 1) {
        int a = (t >= off) ? eoff[t - off] : 0;
        __syncthreads();
        eoff[t] += a;
        __syncthreads();
    }
    int excl = eoff[t] - v;
    __syncthreads();
    eoff[t] = excl;
    __syncthreads();
    for (int i = t; i < cnt; i += 256) {
        int s = ei[base + i], d = ei[E + base + i];
        int b = d >> 9;
        int slot = eoff[b] + atomicAdd(&ecur[b], 1);
        sbuf[slot] = make_int2(s, d);
    }
    __syncthreads();
    if (t < nb && eh[t]) gbase[t] = atomicAdd(&bcur[t], eh[t]);
    __syncthreads();
    for (int i = t; i < cnt; i += 256) {
        int2 e = sbuf[i];
        int b = e.y >> 9;
        binned[gbase[b] + (i - eoff[b])] = e;
    }
}

__global__ __launch_bounds__(256) void k_csr512(const int2* __restrict__ binned,
                                                const int* __restrict__ bstart,
                                                int* __restrict__ rowstart,
                                                int* __restrict__ col, int N, int E) {
    __shared__ int h[512], cur[512], sc[512];
    int t = threadIdx.x, b = blockIdx.x;
    int es = bstart[b], ee = bstart[b + 1];
    for (int i = t; i < 512; i += 256) h[i] = 0;
    __syncthreads();
    for (int i = es + t; i < ee; i += 256) atomicAdd(&h[binned[i].y & 511], 1);
    __syncthreads();
    for (int i = t; i < 512; i += 256) sc[i] = h[i];
    __syncthreads();
    for (int off = 1; off < 512; off <<= 1) {
        int i0 = t, i1 = t + 256;
        int a0 = (i0 >= off) ? sc[i0 - off] : 0;
        int a1 = (i1 >= off) ? sc[i1 - off] : 0;
        __syncthreads();
        sc[i0] += a0; sc[i1] += a1;
        __syncthreads();
    }
    for (int i = t; i < 512; i += 256) {
        int excl = sc[i] - h[i];
        cur[i] = excl;
        int node = (b << 9) + i;
        if (node < N) rowstart[node] = es + excl;
    }
    __syncthreads();
    for (int i = es + t; i < ee; i += 256) {
        int2 e = binned[i];
        int p = atomicAdd(&cur[e.y & 511], 1);
        col[es + p] = e.x;
    }
    if (b == 0 && t == 0) rowstart[N] = E;
}

// ---------------- CSR gather: A[:,0:128] = sum over in-edges of A[src,128:256] --------
// R12: deeper per-row unroll -> VGPR/occupancy cliff, reverted. R15: packed-f32
// accumulate wall-NEUTRAL -> not VALU-bound. R17: cross-node chain overlap (two
// 32-lane half-waves, one node each): 59->56.4 us, VALUBusy 46->32. Now bound by
// random 256B-granule L3 traffic (~207 MB @ ~3.7 TB/s) — near pattern ceiling;
// do not spend more rounds here without a traffic-reduction idea that survives
// the 0.0156 absmax budget.

__global__ __launch_bounds__(256) void k_gather_bf(const int* __restrict__ rowstart,
                                                   const int* __restrict__ col,
                                                   ushort* __restrict__ A, int N) {
    int t = threadIdx.x;
    int lane = t & 63;
    int node = blockIdx.x * 8 + (t >> 6) * 2 + (lane >> 5);
    int sub = (lane >> 4) & 1; // edge slot within node (0/1)
    int chunk = lane & 15;     // 16B chunk in row
    if (node >= N) return;
    int s = rowstart[node], e = rowstart[node + 1];
    const char* hb = (const char*)A; // row r's h-half at byte r*512 + 256
    unsigned coff = (unsigned)chunk * 16u + 256u;
    f32x2 acc[4];
#pragma unroll
    for (int d = 0; d < 4; ++d) acc[d] = (f32x2){0.f, 0.f};
    int i = s + sub;
    if (i + 6 < e) {
        int c0 = col[i], c1 = col[i + 2], c2 = col[i + 4], c3 = col[i + 6];
        while (true) {
            int j = i + 8;
            bool more = (j + 6 < e);
            int n0 = 0, n1 = 0, n2 = 0, n3 = 0;
            if (more) { n0 = col[j]; n1 = col[j + 2]; n2 = col[j + 4]; n3 = col[j + 6]; }
            u32x4 v0 = *(const u32x4*)(hb + ((unsigned)c0 * 512u + coff));
            u32x4 v1 = *(const u32x4*)(hb + ((unsigned)c1 * 512u + coff));
            u32x4 v2 = *(const u32x4*)(hb + ((unsigned)c2 * 512u + coff));
            u32x4 v3 = *(const u32x4*)(hb + ((unsigned)c3 * 512u + coff));
#pragma unroll
            for (int d = 0; d < 4; ++d) {
                f32x2 t0, t1, t2, t3;
                t0.x = __uint_as_float(v0[d] << 16);
                t0.y = __uint_as_float(v0[d] & 0xffff0000u);
                t1.x = __uint_as_float(v1[d] << 16);
                t1.y = __uint_as_float(v1[d] & 0xffff0000u);
                t2.x = __uint_as_float(v2[d] << 16);
                t2.y = __uint_as_float(v2[d] & 0xffff0000u);
                t3.x = __uint_as_float(v3[d] << 16);
                t3.y = __uint_as_float(v3[d] & 0xffff0000u);
                acc[d] += (t0 + t1) + (t2 + t3);
            }
            i = j;
            if (!more) break;
            c0 = n0; c1 = n1; c2 = n2; c3 = n3;
        }
    }
    for (; i < e; i += 2) {
        int c0 = col[i];
        u32x4 v0 = *(const u32x4*)(hb + ((unsigned)c0 * 512u + coff));
#pragma unroll
        for (int d = 0; d < 4; ++d) {
            f32x2 t0;
            t0.x = __uint_as_float(v0[d] << 16);
            t0.y = __uint_as_float(v0[d] & 0xffff0000u);
            acc[d] += t0;
        }
    }
    // reduce the 2 edge slots: lane l <-> l^16 stays within each 32-lane half
#pragma unroll
    for (int d = 0; d < 4; ++d) {
        acc[d].x += __shfl_xor(acc[d].x, 16);
        acc[d].y += __shfl_xor(acc[d].y, 16);
    }
    if (sub == 0) {
        union { ushort u[8]; bf16x8 v; } o;
#pragma unroll
        for (int d = 0; d < 4; ++d) {
            o.u[2 * d] = f2bf(acc[d].x);
            o.u[2 * d + 1] = f2bf(acc[d].y);
        }
        *(bf16x8*)(A + (size_t)node * 256 + chunk * 8) = o.v;
    }
}

// ---------------- fused GRU GEMM (K=256 over [s|h]); h state bf16-only --------------
// R8: acc spill to scratch is catastrophic (1.3 GB HBM) — watch VGPR on any change.
// R16: block-level col-split (grid x2) raised occupancy 19->27% and cut kernel time
// 80->68 us but REGRESSED wall (doubled A-staging traffic + launches).
// R18: same occupancy gain traffic-neutrally — each wave owns 16 cols x 4 gates
// (acc[4][4] = 64 AGPR), block loops ch=0,1 over col halves reusing the staged
// A-tile and acc registers. ~76 VGPR + 64 AGPR = ~140 regs -> launch_bounds(256,3)
// (cap 170, no spill risk) -> 3 waves/SIMD. A-fetch stays ~26 MB, grid 1563.

#define LDA 264
__global__ __launch_bounds__(256, 3) void k_gru_mfma(
    const ushort* __restrict__ A, const ushort* __restrict__ Bc2,
    const float* __restrict__ bias, ushort* __restrict__ Ah) {
    __shared__ ushort As[64 * LDA];
    int t = threadIdx.x;
    int rowb = blockIdx.x << 6;
    for (int c = t; c < 2048; c += 256) {
        int r = c >> 5, off = (c & 31) * 8;
        *(bf16x8*)(As + r * LDA + off) =
            *(const bf16x8*)(A + (size_t)(rowb + r) * 256 + off);
    }
    __syncthreads();
    int w = t >> 6, lane = t & 63;
    int quad = lane >> 4, tn = lane & 15;
#pragma unroll 1
    for (int ch = 0; ch < 2; ++ch) {
        int wct = ch * 4 + w; // col-tile (16 cols) within each gate, 0..7
        f32x4 acc[4][4];
#pragma unroll
        for (int rt = 0; rt < 4; ++rt)
#pragma unroll
            for (int g = 0; g < 4; ++g) acc[rt][g] = (f32x4){0.f, 0.f, 0.f, 0.f};
        for (int ks = 0; ks < 8; ++ks) {
            int k0 = ks * 32 + quad * 8;
            bf16x8 bfr[4];
#pragma unroll
            for (int g = 0; g < 4; ++g) {
                int ct = g * 8 + wct;
                bfr[g] = *(const bf16x8*)(Bc2 + (size_t)((ct * 8 + ks) * 64 + lane) * 8);
            }
            bf16x8 af[4];
#pragma unroll
            for (int rt = 0; rt < 4; ++rt)
                af[rt] = *(const bf16x8*)(As + (rt * 16 + tn) * LDA + k0);
#pragma unroll
            for (int rt = 0; rt < 4; ++rt)
#pragma unroll
                for (int g = 0; g < 4; ++g)
                    acc[rt][g] = __builtin_amdgcn_mfma_f32_16x16x32_bf16(
                        af[rt], bfr[g], acc[rt][g], 0, 0, 0);
        }
        int cc = wct * 16 + tn;
        float br = bias[cc], bz = bias[128 + cc], bin = bias[256 + cc],
              bhn = bias[384 + cc];
#pragma unroll
        for (int rt = 0; rt < 4; ++rt)
#pragma unroll
            for (int r = 0; r < 4; ++r) {
                int rl = rt * 16 + quad * 4 + r;
                int row = rowb + rl;
                float ur = acc[rt][0][r] + br;
                float uz = acc[rt][1][r] + bz;
                float xin = acc[rt][2][r] + bin;
                float xhn = acc[rt][3][r] + bhn;
                float rr = 1.f / (1.f + __expf(-ur));
                float zz = 1.f / (1.f + __expf(-uz));
                float xt = xin + rr * xhn;
                float ex = __expf(2.f * fminf(fmaxf(xt, -15.f), 15.f));
                float nn = (ex - 1.f) / (ex + 1.f);
                float ho = bf2f(As[rl * LDA + 128 + cc]);
                float hv = (1.f - zz) * nn + zz * ho;
                Ah[(size_t)row * 256 + cc] = f2bf(hv);
            }
    }
}

// ---------------- MFMA GEMM (fc1) with fused BN-stats ----------

#define LDA2 136
__global__ __launch_bounds__(256, 2) void k_mm_mfma(
    const ushort* __restrict__ Ain, int astride, const ushort* __restrict__ B2,
    ushort* __restrict__ mo, float* __restrict__ statsl, int N) {
    __shared__ ushort As[64 * LDA2];
    int t = threadIdx.x;
    int rowb = blockIdx.x << 6;
    for (int c = t; c < 1024; c += 256) {
        int r = c >> 4, off = (c & 15) * 8;
        *(bf16x8*)(As + r * LDA2 + off) =
            *(const bf16x8*)(Ain + (size_t)(rowb + r) * astride + off);
    }
    __syncthreads();
    int w = t >> 6, lane = t & 63;
    int quad = lane >> 4, tn = lane & 15;
    f32x4 acc[4][2];
#pragma unroll
    for (int rt = 0; rt < 4; ++rt)
#pragma unroll
        for (int c2 = 0; c2 < 2; ++c2) acc[rt][c2] = (f32x4){0.f, 0.f, 0.f, 0.f};
    for (int ks = 0; ks < 4; ++ks) {
        int k0 = ks * 32 + quad * 8;
        bf16x8 bfr[2];
#pragma unroll
        for (int c2 = 0; c2 < 2; ++c2) {
            int ct = w * 2 + c2;
            bfr[c2] = *(const bf16x8*)(B2 + (size_t)((ct * 4 + ks) * 64 + lane) * 8);
        }
        bf16x8 af[4];
#pragma unroll
        for (int rt = 0; rt < 4; ++rt)
            af[rt] = *(const bf16x8*)(As + (rt * 16 + tn) * LDA2 + k0);
#pragma unroll
        for (int rt = 0; rt < 4; ++rt)
#pragma unroll
            for (int c2 = 0; c2 < 2; ++c2)
                acc[rt][c2] = __builtin_amdgcn_mfma_f32_16x16x32_bf16(
                    af[rt], bfr[c2], acc[rt][c2], 0, 0, 0);
    }
#pragma unroll
    for (int c2 = 0; c2 < 2; ++c2) {
        int col = w * 32 + c2 * 16 + tn;
        float s = 0.f, s2 = 0.f;
#pragma unroll
        for (int rt = 0; rt < 4; ++rt)
#pragma unroll
            for (int r = 0; r < 4; ++r) {
                int row = rowb + rt * 16 + quad * 4 + r;
                float v = acc[rt][c2][r];
                mo[row * 128 + col] = f2bf(v);
                if (row < N) { s += v; s2 += v * v; }
            }
        s += __shfl_xor(s, 16);
        s += __shfl_xor(s, 32);
        s2 += __shfl_xor(s2, 16);
        s2 += __shfl_xor(s2, 32);
        if (quad == 0) {
            int slice = blockIdx.x & 63;
            atomicAdd(&statsl[(slice * 2 + 0) * 128 + col], s);
            atomicAdd(&statsl[(slice * 2 + 1) * 128 + col], s2);
        }
    }
}

// ---------------- BN finalize / pool / head ----------------

__global__ void k_bnfinal(const float* __restrict__ statsl, float* __restrict__ stats,
                          const float* __restrict__ gamma,
                          const float* __restrict__ beta, float n) {
    int j = threadIdx.x;
    if (j < HID) {
        float s = 0.f, s2 = 0.f;
        for (int sl = 0; sl < 64; ++sl) {
            s += statsl[(sl * 2 + 0) * 128 + j];
            s2 += statsl[(sl * 2 + 1) * 128 + j];
        }
        float mu = s / n;
        float var = s2 / n - mu * mu;
        float sc = gamma[j] * rsqrtf(var + BN_EPS);
        stats[256 + j] = sc;
        stats[384 + j] = beta[j] - mu * sc;
    }
}

// atomic-light pool: block = (graph, quarter), rows contiguous via gstart
__global__ __launch_bounds__(256) void k_pool(const ushort* __restrict__ y,
                                              const float* __restrict__ stats,
                                              const int* __restrict__ gstart,
                                              float* __restrict__ gsum) {
    int g = blockIdx.x >> 2, q = blockIdx.x & 3;
    int f = threadIdx.x & 127, half = threadIdx.x >> 7;
    int gs = gstart[g], ge = gstart[g + 1];
    int len = ge - gs;
    int r0 = gs + ((len * q) >> 2), r1 = gs + ((len * (q + 1)) >> 2);
    float sc = stats[256 + f], sh = stats[384 + f];
    float acc = 0.f;
    for (int n = r0 + half; n < r1; n += 2)
        acc += fmaxf(bf2f(y[n * HID + f]) * sc + sh, 0.f);
    __shared__ float ls[2][HID];
    ls[half][f] = acc;
    __syncthreads();
    if (half == 0) atomicAdd(&gsum[g * HID + f], ls[0][f] + ls[1][f]);
}

__global__ void k_head(const float* __restrict__ gsum, const int* __restrict__ gstart,
                       const float* __restrict__ w2, const float* __restrict__ b2,
                       float* __restrict__ out) {
    int g = blockIdx.x * blockDim.x + threadIdx.x;
    if (g >= NGRAPHS) return;
    float cnt = (float)(gstart[g + 1] - gstart[g]);
    float inv = 1.0f / fmaxf(cnt, 1.0f);
    float logits[NCLASSES];
    float mx = -1e30f;
    for (int c = 0; c < NCLASSES; ++c) {
        float acc = b2[c];
        for (int f = 0; f < HID; ++f) acc += gsum[g * HID + f] * inv * w2[c * HID + f];
        logits[c] = acc;
        mx = fmaxf(mx, acc);
    }
    float se = 0.f;
    for (int c = 0; c < NCLASSES; ++c) se += expf(logits[c] - mx);
    float lse = mx + logf(se);
    for (int c = 0; c < NCLASSES; ++c) out[g * NCLASSES + c] = logits[c] - lse;
}

// ---------------- launch ----------------

extern "C" void kernel_launch(void* const* d_in, const int* in_sizes, int n_in,
                              void* d_out, int out_size, void* d_ws, size_t ws_size,
                              hipStream_t stream) {
    const float* x     = (const float*)d_in[0];
    const int*   ei    = (const int*)d_in[1];
    const int*   batch = (const int*)d_in[2];
    const float* ggnnw = (const float*)d_in[3];
    const float* w_ih  = (const float*)d_in[4];
    const float* w_hh  = (const float*)d_in[5];
    const float* b_ih  = (const float*)d_in[6];
    const float* b_hh  = (const float*)d_in[7];
    const float* fc1_w = (const float*)d_in[8];
    // d_in[9] fc1_b: cancels exactly in training-mode BN -> unused
    const float* gamma = (const float*)d_in[10];
    const float* beta  = (const float*)d_in[11];
    const float* fc2_w = (const float*)d_in[12];
    const float* fc2_b = (const float*)d_in[13];
    float* out = (float*)d_out;

    const int N = in_sizes[0] / HID; // 100000
    const int E = in_sizes[1] / 2;   // 1600000
    const int nblk64 = (N + 63) / 64;
    const int P = nblk64 * 64;
    const int nbuck = (N + 511) >> 9; // 196

    char* w = (char*)d_ws;
    auto alloc = [&](size_t bytes) -> char* {
        char* p = w;
        w += (bytes + 255) & ~(size_t)255;
        return p;
    };
    ushort* A   = (ushort*)alloc(sizeof(ushort) * (size_t)P * 256); // [s | h] bf16
    ushort* y   = (ushort*)alloc(sizeof(ushort) * (size_t)P * HID); // fc1 output
    int2*   binned = (int2*)y; // alias: binned dead before k_mm writes y
    ushort* Bc2 = (ushort*)alloc(sizeof(ushort) * NLAYERS * 512 * 256);
    float*  C   = (float*)alloc(sizeof(float) * NLAYERS * 128 * 384);
    ushort* f1b = (ushort*)alloc(sizeof(ushort) * HID * HID);
    float*  bias = (float*)alloc(sizeof(float) * 512);
    int* rowstart = (int*)alloc(sizeof(int) * (N + 4));
    int* colb     = (int*)alloc(sizeof(int) * E);
    int* bstart   = (int*)alloc(sizeof(int) * (nbuck + 4));
    int* bcur     = (int*)alloc(sizeof(int) * (nbuck + 4));
    int* gstart   = (int*)alloc(sizeof(int) * (NGRAPHS + 4));
    // zero-initialized region: bhist, statsl (64 slices x 2 x 128), stats, gsum
    size_t zelems = (size_t)nbuck + 64 * 2 * 128 + 512 + NGRAPHS * HID;
    char* zbase = alloc(zelems * 4);
    int*   bhist  = (int*)zbase;
    float* statsl = (float*)(bhist + nbuck);
    float* stats  = statsl + 64 * 2 * 128;
    float* gsum   = stats + 512;

    hipMemsetAsync(zbase, 0, zelems * 4, stream);

    k_init_x<<<(N * HID + 255) / 256, 256, 0, stream>>>(x, A, N);
    k_wgemm<<<NLAYERS * 128, 128, 0, stream>>>(ggnnw, w_ih, b_ih, b_hh, C, bias);
    k_build_Bc<<<(NLAYERS * 512 * 256 + 255) / 256, 256, 0, stream>>>(C, w_hh, Bc2);
    k_cvt_fc1<<<(16384 + 255) / 256, 256, 0, stream>>>(fc1_w, f1b);

    // staged CSR build (+ gstart fused into bhist dispatch)
    int nchunk = (E + CHUNK - 1) / CHUNK;
    int ngblk = (N + 256) / 256;
    k_bhist<<<nchunk + ngblk, 256, 0, stream>>>(ei, E, nbuck, bhist, batch, gstart, N,
                                                nchunk);
    k_bscan<<<1, 256, 0, stream>>>(bhist, nbuck, bstart, bcur, E);
    k_binfill<<<nchunk, 256, 0, stream>>>(ei, E, nbuck, bcur, binned);
    k_csr512<<<nbuck, 256, 0, stream>>>(binned, bstart, rowstart, colb, N, E);

    for (int l = 0; l < NLAYERS; ++l) {
        k_gather_bf<<<(N + 7) / 8, 256, 0, stream>>>(rowstart, colb, A, N);
        k_gru_mfma<<<nblk64, 256, 0, stream>>>(A, Bc2 + (size_t)l * 512 * 256,
                                               bias, A + 128);
    }

    // head: fc1 (+fused BN stats) -> BN finalize -> pool -> fc2 -> log_softmax
    k_mm_mfma<<<nblk64, 256, 0, stream>>>(A + 128, 256, f1b, y, statsl, N);
    k_bnfinal<<<1, 128, 0, stream>>>(statsl, stats, gamma, beta, (float)N);
    k_pool<<<NGRAPHS * 4, 256, 0, stream>>>(y, stats, gstart, gsum);
    k_head<<<1, 256, 0, stream>>>(gsum, gstart, fc2_w, fc2_b, out);
}

// Round 5
// 703.730 us; speedup vs baseline: 1.5945x; 1.5945x over previous
//
#include <hip/hip_runtime.h>
#include <math.h>

#define HID 128
#define NLAYERS 4
#define NGRAPHS 200
#define NCLASSES 10
#define BN_EPS 1e-5f

typedef short bf16x8 __attribute__((ext_vector_type(8)));
typedef float f32x4 __attribute__((ext_vector_type(4)));
typedef float f32x2 __attribute__((ext_vector_type(2)));
typedef unsigned int u32x4 __attribute__((ext_vector_type(4)));

__device__ __forceinline__ ushort f2bf(float f) {
    unsigned u = __float_as_uint(f);
    u = (u + 0x7fffu + ((u >> 16) & 1u)) >> 16;
    return (ushort)u;
}
__device__ __forceinline__ float bf2f(unsigned us) { return __uint_as_float(us << 16); }

// ---------------- prep kernels ----------------

// A[:,128:256] = bf16(x)  (h state lives only in A's h-half, bf16)
__global__ void k_init_x(const float* __restrict__ x, ushort* __restrict__ A, int N) {
    int idx = blockIdx.x * blockDim.x + threadIdx.x;
    if (idx < N * HID) {
        int n = idx >> 7, c = idx & 127;
        A[n * 256 + 128 + c] = f2bf(x[idx]);
    }
}

// C[l][k][j] = sum_o W_l[k][o] * w_ih[j][o]; blocks 0..3 also fold the bias vector.
__global__ __launch_bounds__(128) void k_wgemm(const float* __restrict__ W,
                                               const float* __restrict__ w_ih,
                                               const float* __restrict__ b_ih,
                                               const float* __restrict__ b_hh,
                                               float* __restrict__ C,
                                               float* __restrict__ bias) {
    int l = blockIdx.x >> 7, k = blockIdx.x & 127;
    __shared__ float wrow[128];
    wrow[threadIdx.x] = W[(l << 14) + k * 128 + threadIdx.x];
    __syncthreads();
    for (int j = threadIdx.x; j < 384; j += 128) {
        float acc = 0.f;
#pragma unroll 4
        for (int o = 0; o < 128; ++o) acc += wrow[o] * w_ih[j * 128 + o];
        C[((size_t)l * 128 + k) * 384 + j] = acc;
    }
    if (blockIdx.x < 4) {
        int j = blockIdx.x * 128 + threadIdx.x; // 0..511
        float v;
        if (j < 256)      v = b_ih[j] + b_hh[j];
        else if (j < 384) v = b_ih[j];
        else              v = b_hh[j - 128];
        bias[j] = v;
    }
}

// Per-layer combined GRU weights in MFMA-fragment order (K=256 over [s|h], 512 outs)
__global__ void k_build_Bc(const float* __restrict__ C, const float* __restrict__ w_hh,
                           ushort* __restrict__ Bc2) {
    int idx = blockIdx.x * blockDim.x + threadIdx.x;
    if (idx >= NLAYERS * 512 * 256) return;
    int jf = idx & 7, lane = (idx >> 3) & 63, ks = (idx >> 9) & 7, ct = (idx >> 12) & 31;
    int l = idx >> 17;
    int o = ct * 16 + (lane & 15);
    int k = ks * 32 + (lane >> 4) * 8 + jf;
    float v;
    if (k < 128)      v = (o < 384) ? C[((size_t)l * 128 + k) * 384 + o] : 0.f;
    else if (o < 256) v = w_hh[o * 128 + (k - 128)];
    else if (o < 384) v = 0.f;
    else              v = w_hh[(o - 128) * 128 + (k - 128)];
    Bc2[idx] = f2bf(v);
}

// fc1_w[o][k] -> fragment order (K=128: ks in [0,4), ct in [0,8))
__global__ void k_cvt_fc1(const float* __restrict__ w, ushort* __restrict__ B2) {
    int idx = blockIdx.x * blockDim.x + threadIdx.x;
    if (idx >= 16384) return;
    int j = idx & 7, lane = (idx >> 3) & 63, ks = (idx >> 9) & 3, ct = idx >> 11;
    int o = ct * 16 + (lane & 15);
    int k = ks * 32 + (lane >> 4) * 8 + j;
    B2[idx] = f2bf(w[o * 128 + k]);
}

// ---------------- CSR build: staged counting-sort (no write amplification) ----------
// R10 lesson: NO dynamically-indexed register arrays (-> scratch). Scatter pass
// re-reads the chunk from global (L1/L2-hot after the hist pass).

#define CHUNK 2048

// blocks [0,nchunk): per-chunk bucket histogram; blocks [nchunk, ...): gstart
__global__ __launch_bounds__(256) void k_bhist(const int* __restrict__ ei, int E,
                                               int nb, int* __restrict__ bhist,
                                               const int* __restrict__ batch,
                                               int* __restrict__ gstart, int N,
                                               int nchunk) {
    if ((int)blockIdx.x < nchunk) {
        __shared__ int lh[256];
        int t = threadIdx.x;
        lh[t] = 0;
        __syncthreads();
        int base = blockIdx.x * CHUNK;
        int end = min(base + CHUNK, E);
        for (int i = base + t; i < end; i += 256) atomicAdd(&lh[ei[E + i] >> 9], 1);
        __syncthreads();
        if (t < nb && lh[t]) atomicAdd(&bhist[t], lh[t]);
    } else {
        int n = (blockIdx.x - nchunk) * 256 + threadIdx.x;
        if (n > N) return;
        int curb = (n == N) ? NGRAPHS : batch[n];
        int prev = (n == 0) ? -1 : batch[n - 1];
        for (int g = prev + 1; g <= curb; ++g) gstart[g] = n;
    }
}

__global__ void k_bscan(const int* __restrict__ bhist, int nb, int* __restrict__ bstart,
                        int* __restrict__ bcur, int E) {
    __shared__ int s[256];
    int t = threadIdx.x;
    int v = (t < nb) ? bhist[t] : 0;
    s[t] = v;
    __syncthreads();
    for (int off = 1; off < 256; off <<= 1) {
        int a = (t >= off) ? s[t - off] : 0;
        __syncthreads();
        s[t] += a;
        __syncthreads();
    }
    if (t < nb) { int ex = s[t] - v; bstart[t] = ex; bcur[t] = ex; }
    if (t == 0) bstart[nb] = E;
}

__global__ __launch_bounds__(256) void k_binfill(const int* __restrict__ ei, int E,
                                                 int nb, int* __restrict__ bcur,
                                                 int2* __restrict__ binned) {
    __shared__ int eh[256], eoff[256], ecur[256], gbase[256];
    __shared__ int2 sbuf[CHUNK];
    int t = threadIdx.x;
    eh[t] = 0; ecur[t] = 0;
    __syncthreads();
    int base = blockIdx.x * CHUNK;
    int cnt = min(CHUNK, E - base);
    for (int i = t; i < cnt; i += 256) atomicAdd(&eh[ei[E + base + i] >> 9], 1);
    __syncthreads();
    int v = eh[t];
    eoff[t] = v;
    __syncthreads();
    for (int off = 1; off < 256; off <<= 1) {
        int a = (t >= off) ? eoff[t - off] : 0;
        __syncthreads();
        eoff[t] += a;
        __syncthreads();
    }
    int excl = eoff[t] - v;
    __syncthreads();
    eoff[t] = excl;
    __syncthreads();
    for (int i = t; i < cnt; i += 256) {
        int s = ei[base + i], d = ei[E + base + i];
        int b = d >> 9;
        int slot = eoff[b] + atomicAdd(&ecur[b], 1);
        sbuf[slot] = make_int2(s, d);
    }
    __syncthreads();
    if (t < nb && eh[t]) gbase[t] = atomicAdd(&bcur[t], eh[t]);
    __syncthreads();
    for (int i = t; i < cnt; i += 256) {
        int2 e = sbuf[i];
        int b = e.y >> 9;
        binned[gbase[b] + (i - eoff[b])] = e;
    }
}

__global__ __launch_bounds__(256) void k_csr512(const int2* __restrict__ binned,
                                                const int* __restrict__ bstart,
                                                int* __restrict__ rowstart,
                                                int* __restrict__ col, int N, int E) {
    __shared__ int h[512], cur[512], sc[512];
    int t = threadIdx.x, b = blockIdx.x;
    int es = bstart[b], ee = bstart[b + 1];
    for (int i = t; i < 512; i += 256) h[i] = 0;
    __syncthreads();
    for (int i = es + t; i < ee; i += 256) atomicAdd(&h[binned[i].y & 511], 1);
    __syncthreads();
    for (int i = t; i < 512; i += 256) sc[i] = h[i];
    __syncthreads();
    for (int off = 1; off < 512; off <<= 1) {
        int i0 = t, i1 = t + 256;
        int a0 = (i0 >= off) ? sc[i0 - off] : 0;
        int a1 = (i1 >= off) ? sc[i1 - off] : 0;
        __syncthreads();
        sc[i0] += a0; sc[i1] += a1;
        __syncthreads();
    }
    for (int i = t; i < 512; i += 256) {
        int excl = sc[i] - h[i];
        cur[i] = excl;
        int node = (b << 9) + i;
        if (node < N) rowstart[node] = es + excl;
    }
    __syncthreads();
    for (int i = es + t; i < ee; i += 256) {
        int2 e = binned[i];
        int p = atomicAdd(&cur[e.y & 511], 1);
        col[es + p] = e.x;
    }
    if (b == 0 && t == 0) rowstart[N] = E;
}

// ---------------- CSR gather: A[:,0:128] = sum over in-edges of A[src,128:256] --------
// R17: cross-node chain overlap (two 32-lane half-waves, one node each): 59->56.4us,
// VALUBusy 46->32 -> concurrency-limited, not VALU. R19: 2-stage software pipeline:
// two live row groups (a/b) + cols prefetched one full group ahead, rows issued
// BEFORE next cols so the in-order vmcnt wait on accum(a) retires only the oldest
// prefix. 8 row-loads in flight per lane in steady state (was 4).
// VGPR budget must stay <=64 (waves/SIMD halves past 64 — m69).

__device__ __forceinline__ void acc8(f32x2 (&acc)[4], u32x4 v) {
#pragma unroll
    for (int d = 0; d < 4; ++d) {
        f32x2 t;
        t.x = __uint_as_float(v[d] << 16);
        t.y = __uint_as_float(v[d] & 0xffff0000u);
        acc[d] += t;
    }
}

__global__ __launch_bounds__(256) void k_gather_bf(const int* __restrict__ rowstart,
                                                   const int* __restrict__ col,
                                                   ushort* __restrict__ A, int N) {
    int t = threadIdx.x;
    int lane = t & 63;
    int node = blockIdx.x * 8 + (t >> 6) * 2 + (lane >> 5);
    int sub = (lane >> 4) & 1; // edge slot within node (0/1)
    int chunk = lane & 15;     // 16B chunk in row
    if (node >= N) return;
    int s = rowstart[node], e = rowstart[node + 1];
    const char* hb = (const char*)A; // row r's h-half at byte r*512 + 256
    unsigned coff = (unsigned)chunk * 16u + 256u;
#define ROWLD(c) (*(const u32x4*)(hb + ((unsigned)(c) * 512u + coff)))
    f32x2 acc[4];
#pragma unroll
    for (int d = 0; d < 4; ++d) acc[d] = (f32x2){0.f, 0.f};
    int i = s + sub;
    if (i + 14 < e) {
        // prologue: rows of G0 and G1 in flight, cols of G2 (if any) in regs
        int c0 = col[i], c1 = col[i + 2], c2 = col[i + 4], c3 = col[i + 6];
        u32x4 a0 = ROWLD(c0), a1 = ROWLD(c1), a2 = ROWLD(c2), a3 = ROWLD(c3);
        c0 = col[i + 8]; c1 = col[i + 10]; c2 = col[i + 12]; c3 = col[i + 14];
        u32x4 b0 = ROWLD(c0), b1 = ROWLD(c1), b2 = ROWLD(c2), b3 = ROWLD(c3);
        i += 16;
        int d0 = 0, d1 = 0, d2 = 0, d3 = 0;
        bool haveC = (i + 6 < e);
        if (haveC) { d0 = col[i]; d1 = col[i + 2]; d2 = col[i + 4]; d3 = col[i + 6]; i += 8; }
        while (true) {
            // phase A: consume a (oldest in queue), refill a from d-cols, then next cols
            acc8(acc, a0); acc8(acc, a1); acc8(acc, a2); acc8(acc, a3);
            if (!haveC) { acc8(acc, b0); acc8(acc, b1); acc8(acc, b2); acc8(acc, b3); break; }
            a0 = ROWLD(d0); a1 = ROWLD(d1); a2 = ROWLD(d2); a3 = ROWLD(d3);
            haveC = (i + 6 < e);
            if (haveC) { d0 = col[i]; d1 = col[i + 2]; d2 = col[i + 4]; d3 = col[i + 6]; i += 8; }
            // phase B: consume b, refill b
            acc8(acc, b0); acc8(acc, b1); acc8(acc, b2); acc8(acc, b3);
            if (!haveC) { acc8(acc, a0); acc8(acc, a1); acc8(acc, a2); acc8(acc, a3); break; }
            b0 = ROWLD(d0); b1 = ROWLD(d1); b2 = ROWLD(d2); b3 = ROWLD(d3);
            haveC = (i + 6 < e);
            if (haveC) { d0 = col[i]; d1 = col[i + 2]; d2 = col[i + 4]; d3 = col[i + 6]; i += 8; }
        }
    }
    // mid tail: full 4-edge groups, 4 in flight
    while (i + 6 < e) {
        int c0 = col[i], c1 = col[i + 2], c2 = col[i + 4], c3 = col[i + 6];
        u32x4 v0 = ROWLD(c0), v1 = ROWLD(c1), v2 = ROWLD(c2), v3 = ROWLD(c3);
        acc8(acc, v0); acc8(acc, v1); acc8(acc, v2); acc8(acc, v3);
        i += 8;
    }
    // singles, 2-deep pipelined
    if (i < e) {
        u32x4 w0 = ROWLD(col[i]);
        for (i += 2; i < e; i += 2) {
            u32x4 w1 = ROWLD(col[i]);
            acc8(acc, w0);
            w0 = w1;
        }
        acc8(acc, w0);
    }
#undef ROWLD
    // reduce the 2 edge slots: lane l <-> l^16 stays within each 32-lane half
#pragma unroll
    for (int d = 0; d < 4; ++d) {
        acc[d].x += __shfl_xor(acc[d].x, 16);
        acc[d].y += __shfl_xor(acc[d].y, 16);
    }
    if (sub == 0) {
        union { ushort u[8]; bf16x8 v; } o;
#pragma unroll
        for (int d = 0; d < 4; ++d) {
            o.u[2 * d] = f2bf(acc[d].x);
            o.u[2 * d + 1] = f2bf(acc[d].y);
        }
        *(bf16x8*)(A + (size_t)node * 256 + chunk * 8) = o.v;
    }
}

// ---------------- fused GRU GEMM (K=256 over [s|h]); h state bf16-only --------------
// R8/R18: the 128-reg accumulator set spills to scratch at ANY min-waves > 2
// (R18: launch_bounds(256,3) -> 204 MB FETCH + 203 MB WRITE of scratch, wall
// 714->1122). R16: block-level col-split also regressed (traffic). This kernel is
// pinned at min-waves 2 with the full 64x512 per-block tile. Do not touch occupancy.

#define LDA 264
__global__ __launch_bounds__(256, 2) void k_gru_mfma(
    const ushort* __restrict__ A, const ushort* __restrict__ Bc2,
    const float* __restrict__ bias, ushort* __restrict__ Ah) {
    __shared__ ushort As[64 * LDA];
    int t = threadIdx.x;
    int rowb = blockIdx.x << 6;
    for (int c = t; c < 2048; c += 256) {
        int r = c >> 5, off = (c & 31) * 8;
        *(bf16x8*)(As + r * LDA + off) =
            *(const bf16x8*)(A + (size_t)(rowb + r) * 256 + off);
    }
    __syncthreads();
    int w = t >> 6, lane = t & 63;
    int quad = lane >> 4, tn = lane & 15;
    f32x4 acc[4][4][2];
#pragma unroll
    for (int rt = 0; rt < 4; ++rt)
#pragma unroll
        for (int g = 0; g < 4; ++g)
#pragma unroll
            for (int c2 = 0; c2 < 2; ++c2) acc[rt][g][c2] = (f32x4){0.f, 0.f, 0.f, 0.f};
    for (int ks = 0; ks < 8; ++ks) {
        int k0 = ks * 32 + quad * 8;
        bf16x8 bfr[4][2];
#pragma unroll
        for (int g = 0; g < 4; ++g)
#pragma unroll
            for (int c2 = 0; c2 < 2; ++c2) {
                int ct = g * 8 + w * 2 + c2;
                bfr[g][c2] = *(const bf16x8*)(Bc2 + (size_t)((ct * 8 + ks) * 64 + lane) * 8);
            }
        bf16x8 af[4];
#pragma unroll
        for (int rt = 0; rt < 4; ++rt)
            af[rt] = *(const bf16x8*)(As + (rt * 16 + tn) * LDA + k0);
#pragma unroll
        for (int rt = 0; rt < 4; ++rt)
#pragma unroll
            for (int g = 0; g < 4; ++g)
#pragma unroll
                for (int c2 = 0; c2 < 2; ++c2)
                    acc[rt][g][c2] = __builtin_amdgcn_mfma_f32_16x16x32_bf16(
                        af[rt], bfr[g][c2], acc[rt][g][c2], 0, 0, 0);
    }
#pragma unroll
    for (int c2 = 0; c2 < 2; ++c2) {
        int cc = w * 32 + c2 * 16 + tn;
        float br = bias[cc], bz = bias[128 + cc], bin = bias[256 + cc], bhn = bias[384 + cc];
#pragma unroll
        for (int rt = 0; rt < 4; ++rt)
#pragma unroll
            for (int r = 0; r < 4; ++r) {
                int rl = rt * 16 + quad * 4 + r;
                int row = rowb + rl;
                float ur = acc[rt][0][c2][r] + br;
                float uz = acc[rt][1][c2][r] + bz;
                float xin = acc[rt][2][c2][r] + bin;
                float xhn = acc[rt][3][c2][r] + bhn;
                float rr = 1.f / (1.f + __expf(-ur));
                float zz = 1.f / (1.f + __expf(-uz));
                float xt = xin + rr * xhn;
                float ex = __expf(2.f * fminf(fmaxf(xt, -15.f), 15.f));
                float nn = (ex - 1.f) / (ex + 1.f);
                float ho = bf2f(As[rl * LDA + 128 + cc]);
                float hv = (1.f - zz) * nn + zz * ho;
                Ah[(size_t)row * 256 + cc] = f2bf(hv);
            }
    }
}

// ---------------- MFMA GEMM (fc1) with fused BN-stats ----------

#define LDA2 136
__global__ __launch_bounds__(256, 2) void k_mm_mfma(
    const ushort* __restrict__ Ain, int astride, const ushort* __restrict__ B2,
    ushort* __restrict__ mo, float* __restrict__ statsl, int N) {
    __shared__ ushort As[64 * LDA2];
    int t = threadIdx.x;
    int rowb = blockIdx.x << 6;
    for (int c = t; c < 1024; c += 256) {
        int r = c >> 4, off = (c & 15) * 8;
        *(bf16x8*)(As + r * LDA2 + off) =
            *(const bf16x8*)(Ain + (size_t)(rowb + r) * astride + off);
    }
    __syncthreads();
    int w = t >> 6, lane = t & 63;
    int quad = lane >> 4, tn = lane & 15;
    f32x4 acc[4][2];
#pragma unroll
    for (int rt = 0; rt < 4; ++rt)
#pragma unroll
        for (int c2 = 0; c2 < 2; ++c2) acc[rt][c2] = (f32x4){0.f, 0.f, 0.f, 0.f};
    for (int ks = 0; ks < 4; ++ks) {
        int k0 = ks * 32 + quad * 8;
        bf16x8 bfr[2];
#pragma unroll
        for (int c2 = 0; c2 < 2; ++c2) {
            int ct = w * 2 + c2;
            bfr[c2] = *(const bf16x8*)(B2 + (size_t)((ct * 4 + ks) * 64 + lane) * 8);
        }
        bf16x8 af[4];
#pragma unroll
        for (int rt = 0; rt < 4; ++rt)
            af[rt] = *(const bf16x8*)(As + (rt * 16 + tn) * LDA2 + k0);
#pragma unroll
        for (int rt = 0; rt < 4; ++rt)
#pragma unroll
            for (int c2 = 0; c2 < 2; ++c2)
                acc[rt][c2] = __builtin_amdgcn_mfma_f32_16x16x32_bf16(
                    af[rt], bfr[c2], acc[rt][c2], 0, 0, 0);
    }
#pragma unroll
    for (int c2 = 0; c2 < 2; ++c2) {
        int col = w * 32 + c2 * 16 + tn;
        float s = 0.f, s2 = 0.f;
#pragma unroll
        for (int rt = 0; rt < 4; ++rt)
#pragma unroll
            for (int r = 0; r < 4; ++r) {
                int row = rowb + rt * 16 + quad * 4 + r;
                float v = acc[rt][c2][r];
                mo[row * 128 + col] = f2bf(v);
                if (row < N) { s += v; s2 += v * v; }
            }
        s += __shfl_xor(s, 16);
        s += __shfl_xor(s, 32);
        s2 += __shfl_xor(s2, 16);
        s2 += __shfl_xor(s2, 32);
        if (quad == 0) {
            int slice = blockIdx.x & 63;
            atomicAdd(&statsl[(slice * 2 + 0) * 128 + col], s);
            atomicAdd(&statsl[(slice * 2 + 1) * 128 + col], s2);
        }
    }
}

// ---------------- BN finalize / pool / head ----------------

__global__ void k_bnfinal(const float* __restrict__ statsl, float* __restrict__ stats,
                          const float* __restrict__ gamma,
                          const float* __restrict__ beta, float n) {
    int j = threadIdx.x;
    if (j < HID) {
        float s = 0.f, s2 = 0.f;
        for (int sl = 0; sl < 64; ++sl) {
            s += statsl[(sl * 2 + 0) * 128 + j];
            s2 += statsl[(sl * 2 + 1) * 128 + j];
        }
        float mu = s / n;
        float var = s2 / n - mu * mu;
        float sc = gamma[j] * rsqrtf(var + BN_EPS);
        stats[256 + j] = sc;
        stats[384 + j] = beta[j] - mu * sc;
    }
}

// atomic-light pool: block = (graph, quarter), rows contiguous via gstart
__global__ __launch_bounds__(256) void k_pool(const ushort* __restrict__ y,
                                              const float* __restrict__ stats,
                                              const int* __restrict__ gstart,
                                              float* __restrict__ gsum) {
    int g = blockIdx.x >> 2, q = blockIdx.x & 3;
    int f = threadIdx.x & 127, half = threadIdx.x >> 7;
    int gs = gstart[g], ge = gstart[g + 1];
    int len = ge - gs;
    int r0 = gs + ((len * q) >> 2), r1 = gs + ((len * (q + 1)) >> 2);
    float sc = stats[256 + f], sh = stats[384 + f];
    float acc = 0.f;
    for (int n = r0 + half; n < r1; n += 2)
        acc += fmaxf(bf2f(y[n * HID + f]) * sc + sh, 0.f);
    __shared__ float ls[2][HID];
    ls[half][f] = acc;
    __syncthreads();
    if (half == 0) atomicAdd(&gsum[g * HID + f], ls[0][f] + ls[1][f]);
}

__global__ void k_head(const float* __restrict__ gsum, const int* __restrict__ gstart,
                       const float* __restrict__ w2, const float* __restrict__ b2,
                       float* __restrict__ out) {
    int g = blockIdx.x * blockDim.x + threadIdx.x;
    if (g >= NGRAPHS) return;
    float cnt = (float)(gstart[g + 1] - gstart[g]);
    float inv = 1.0f / fmaxf(cnt, 1.0f);
    float logits[NCLASSES];
    float mx = -1e30f;
    for (int c = 0; c < NCLASSES; ++c) {
        float acc = b2[c];
        for (int f = 0; f < HID; ++f) acc += gsum[g * HID + f] * inv * w2[c * HID + f];
        logits[c] = acc;
        mx = fmaxf(mx, acc);
    }
    float se = 0.f;
    for (int c = 0; c < NCLASSES; ++c) se += expf(logits[c] - mx);
    float lse = mx + logf(se);
    for (int c = 0; c < NCLASSES; ++c) out[g * NCLASSES + c] = logits[c] - lse;
}

// ---------------- launch ----------------

extern "C" void kernel_launch(void* const* d_in, const int* in_sizes, int n_in,
                              void* d_out, int out_size, void* d_ws, size_t ws_size,
                              hipStream_t stream) {
    const float* x     = (const float*)d_in[0];
    const int*   ei    = (const int*)d_in[1];
    const int*   batch = (const int*)d_in[2];
    const float* ggnnw = (const float*)d_in[3];
    const float* w_ih  = (const float*)d_in[4];
    const float* w_hh  = (const float*)d_in[5];
    const float* b_ih  = (const float*)d_in[6];
    const float* b_hh  = (const float*)d_in[7];
    const float* fc1_w = (const float*)d_in[8];
    // d_in[9] fc1_b: cancels exactly in training-mode BN -> unused
    const float* gamma = (const float*)d_in[10];
    const float* beta  = (const float*)d_in[11];
    const float* fc2_w = (const float*)d_in[12];
    const float* fc2_b = (const float*)d_in[13];
    float* out = (float*)d_out;

    const int N = in_sizes[0] / HID; // 100000
    const int E = in_sizes[1] / 2;   // 1600000
    const int nblk64 = (N + 63) / 64;
    const int P = nblk64 * 64;
    const int nbuck = (N + 511) >> 9; // 196

    char* w = (char*)d_ws;
    auto alloc = [&](size_t bytes) -> char* {
        char* p = w;
        w += (bytes + 255) & ~(size_t)255;
        return p;
    };
    ushort* A   = (ushort*)alloc(sizeof(ushort) * (size_t)P * 256); // [s | h] bf16
    ushort* y   = (ushort*)alloc(sizeof(ushort) * (size_t)P * HID); // fc1 output
    int2*   binned = (int2*)y; // alias: binned dead before k_mm writes y
    ushort* Bc2 = (ushort*)alloc(sizeof(ushort) * NLAYERS * 512 * 256);
    float*  C   = (float*)alloc(sizeof(float) * NLAYERS * 128 * 384);
    ushort* f1b = (ushort*)alloc(sizeof(ushort) * HID * HID);
    float*  bias = (float*)alloc(sizeof(float) * 512);
    int* rowstart = (int*)alloc(sizeof(int) * (N + 4));
    int* colb     = (int*)alloc(sizeof(int) * E);
    int* bstart   = (int*)alloc(sizeof(int) * (nbuck + 4));
    int* bcur     = (int*)alloc(sizeof(int) * (nbuck + 4));
    int* gstart   = (int*)alloc(sizeof(int) * (NGRAPHS + 4));
    // zero-initialized region: bhist, statsl (64 slices x 2 x 128), stats, gsum
    size_t zelems = (size_t)nbuck + 64 * 2 * 128 + 512 + NGRAPHS * HID;
    char* zbase = alloc(zelems * 4);
    int*   bhist  = (int*)zbase;
    float* statsl = (float*)(bhist + nbuck);
    float* stats  = statsl + 64 * 2 * 128;
    float* gsum   = stats + 512;

    hipMemsetAsync(zbase, 0, zelems * 4, stream);

    k_init_x<<<(N * HID + 255) / 256, 256, 0, stream>>>(x, A, N);
    k_wgemm<<<NLAYERS * 128, 128, 0, stream>>>(ggnnw, w_ih, b_ih, b_hh, C, bias);
    k_build_Bc<<<(NLAYERS * 512 * 256 + 255) / 256, 256, 0, stream>>>(C, w_hh, Bc2);
    k_cvt_fc1<<<(16384 + 255) / 256, 256, 0, stream>>>(fc1_w, f1b);

    // staged CSR build (+ gstart fused into bhist dispatch)
    int nchunk = (E + CHUNK - 1) / CHUNK;
    int ngblk = (N + 256) / 256;
    k_bhist<<<nchunk + ngblk, 256, 0, stream>>>(ei, E, nbuck, bhist, batch, gstart, N,
                                                nchunk);
    k_bscan<<<1, 256, 0, stream>>>(bhist, nbuck, bstart, bcur, E);
    k_binfill<<<nchunk, 256, 0, stream>>>(ei, E, nbuck, bcur, binned);
    k_csr512<<<nbuck, 256, 0, stream>>>(binned, bstart, rowstart, colb, N, E);

    for (int l = 0; l < NLAYERS; ++l) {
        k_gather_bf<<<(N + 7) / 8, 256, 0, stream>>>(rowstart, colb, A, N);
        k_gru_mfma<<<nblk64, 256, 0, stream>>>(A, Bc2 + (size_t)l * 512 * 256,
                                               bias, A + 128);
    }

    // head: fc1 (+fused BN stats) -> BN finalize -> pool -> fc2 -> log_softmax
    k_mm_mfma<<<nblk64, 256, 0, stream>>>(A + 128, 256, f1b, y, statsl, N);
    k_bnfinal<<<1, 128, 0, stream>>>(statsl, stats, gamma, beta, (float)N);
    k_pool<<<NGRAPHS * 4, 256, 0, stream>>>(y, stats, gstart, gsum);
    k_head<<<1, 256, 0, stream>>>(gsum, gstart, fc2_w, fc2_b, out);
}

// Round 6
// 688.626 us; speedup vs baseline: 1.6294x; 1.0219x over previous
//
#include <hip/hip_runtime.h>
#include <math.h>

#define HID 128
#define NLAYERS 4
#define NGRAPHS 200
#define NCLASSES 10
#define BN_EPS 1e-5f

typedef short bf16x8 __attribute__((ext_vector_type(8)));
typedef float f32x4 __attribute__((ext_vector_type(4)));
typedef float f32x2 __attribute__((ext_vector_type(2)));
typedef unsigned int u32x4 __attribute__((ext_vector_type(4)));

__device__ __forceinline__ ushort f2bf(float f) {
    unsigned u = __float_as_uint(f);
    u = (u + 0x7fffu + ((u >> 16) & 1u)) >> 16;
    return (ushort)u;
}
__device__ __forceinline__ float bf2f(unsigned us) { return __uint_as_float(us << 16); }

// ---------------- prep kernels ----------------

// A[:,128:256] = bf16(x)  (h state lives only in A's h-half, bf16)
__global__ void k_init_x(const float* __restrict__ x, ushort* __restrict__ A, int N) {
    int idx = blockIdx.x * blockDim.x + threadIdx.x;
    if (idx < N * HID) {
        int n = idx >> 7, c = idx & 127;
        A[n * 256 + 128 + c] = f2bf(x[idx]);
    }
}

// C[l][k][j] = sum_o W_l[k][o] * w_ih[j][o]; blocks 0..3 also fold the bias vector.
__global__ __launch_bounds__(128) void k_wgemm(const float* __restrict__ W,
                                               const float* __restrict__ w_ih,
                                               const float* __restrict__ b_ih,
                                               const float* __restrict__ b_hh,
                                               float* __restrict__ C,
                                               float* __restrict__ bias) {
    int l = blockIdx.x >> 7, k = blockIdx.x & 127;
    __shared__ float wrow[128];
    wrow[threadIdx.x] = W[(l << 14) + k * 128 + threadIdx.x];
    __syncthreads();
    for (int j = threadIdx.x; j < 384; j += 128) {
        float acc = 0.f;
#pragma unroll 4
        for (int o = 0; o < 128; ++o) acc += wrow[o] * w_ih[j * 128 + o];
        C[((size_t)l * 128 + k) * 384 + j] = acc;
    }
    if (blockIdx.x < 4) {
        int j = blockIdx.x * 128 + threadIdx.x; // 0..511
        float v;
        if (j < 256)      v = b_ih[j] + b_hh[j];
        else if (j < 384) v = b_ih[j];
        else              v = b_hh[j - 128];
        bias[j] = v;
    }
}

// Per-layer combined GRU weights in MFMA-fragment order (K=256 over [s|h], 512 outs)
__global__ void k_build_Bc(const float* __restrict__ C, const float* __restrict__ w_hh,
                           ushort* __restrict__ Bc2) {
    int idx = blockIdx.x * blockDim.x + threadIdx.x;
    if (idx >= NLAYERS * 512 * 256) return;
    int jf = idx & 7, lane = (idx >> 3) & 63, ks = (idx >> 9) & 7, ct = (idx >> 12) & 31;
    int l = idx >> 17;
    int o = ct * 16 + (lane & 15);
    int k = ks * 32 + (lane >> 4) * 8 + jf;
    float v;
    if (k < 128)      v = (o < 384) ? C[((size_t)l * 128 + k) * 384 + o] : 0.f;
    else if (o < 256) v = w_hh[o * 128 + (k - 128)];
    else if (o < 384) v = 0.f;
    else              v = w_hh[(o - 128) * 128 + (k - 128)];
    Bc2[idx] = f2bf(v);
}

// fc1_w[o][k] -> fragment order (K=128: ks in [0,4), ct in [0,8))
__global__ void k_cvt_fc1(const float* __restrict__ w, ushort* __restrict__ B2) {
    int idx = blockIdx.x * blockDim.x + threadIdx.x;
    if (idx >= 16384) return;
    int j = idx & 7, lane = (idx >> 3) & 63, ks = (idx >> 9) & 3, ct = idx >> 11;
    int o = ct * 16 + (lane & 15);
    int k = ks * 32 + (lane >> 4) * 8 + j;
    B2[idx] = f2bf(w[o * 128 + k]);
}

// ---------------- CSR build: staged counting-sort (no write amplification) ----------
// R10 lesson: NO dynamically-indexed register arrays (-> scratch). Scatter pass
// re-reads the chunk from global (L1/L2-hot after the hist pass).

#define CHUNK 2048

// blocks [0,nchunk): per-chunk bucket histogram; blocks [nchunk, ...): gstart
__global__ __launch_bounds__(256) void k_bhist(const int* __restrict__ ei, int E,
                                               int nb, int* __restrict__ bhist,
                                               const int* __restrict__ batch,
                                               int* __restrict__ gstart, int N,
                                               int nchunk) {
    if ((int)blockIdx.x < nchunk) {
        __shared__ int lh[256];
        int t = threadIdx.x;
        lh[t] = 0;
        __syncthreads();
        int base = blockIdx.x * CHUNK;
        int end = min(base + CHUNK, E);
        for (int i = base + t; i < end; i += 256) atomicAdd(&lh[ei[E + i] >> 9], 1);
        __syncthreads();
        if (t < nb && lh[t]) atomicAdd(&bhist[t], lh[t]);
    } else {
        int n = (blockIdx.x - nchunk) * 256 + threadIdx.x;
        if (n > N) return;
        int curb = (n == N) ? NGRAPHS : batch[n];
        int prev = (n == 0) ? -1 : batch[n - 1];
        for (int g = prev + 1; g <= curb; ++g) gstart[g] = n;
    }
}

__global__ void k_bscan(const int* __restrict__ bhist, int nb, int* __restrict__ bstart,
                        int* __restrict__ bcur, int E) {
    __shared__ int s[256];
    int t = threadIdx.x;
    int v = (t < nb) ? bhist[t] : 0;
    s[t] = v;
    __syncthreads();
    for (int off = 1; off < 256; off <<= 1) {
        int a = (t >= off) ? s[t - off] : 0;
        __syncthreads();
        s[t] += a;
        __syncthreads();
    }
    if (t < nb) { int ex = s[t] - v; bstart[t] = ex; bcur[t] = ex; }
    if (t == 0) bstart[nb] = E;
}

__global__ __launch_bounds__(256) void k_binfill(const int* __restrict__ ei, int E,
                                                 int nb, int* __restrict__ bcur,
                                                 int2* __restrict__ binned) {
    __shared__ int eh[256], eoff[256], ecur[256], gbase[256];
    __shared__ int2 sbuf[CHUNK];
    int t = threadIdx.x;
    eh[t] = 0; ecur[t] = 0;
    __syncthreads();
    int base = blockIdx.x * CHUNK;
    int cnt = min(CHUNK, E - base);
    for (int i = t; i < cnt; i += 256) atomicAdd(&eh[ei[E + base + i] >> 9], 1);
    __syncthreads();
    int v = eh[t];
    eoff[t] = v;
    __syncthreads();
    for (int off = 1; off < 256; off <<= 1) {
        int a = (t >= off) ? eoff[t - off] : 0;
        __syncthreads();
        eoff[t] += a;
        __syncthreads();
    }
    int excl = eoff[t] - v;
    __syncthreads();
    eoff[t] = excl;
    __syncthreads();
    for (int i = t; i < cnt; i += 256) {
        int s = ei[base + i], d = ei[E + base + i];
        int b = d >> 9;
        int slot = eoff[b] + atomicAdd(&ecur[b], 1);
        sbuf[slot] = make_int2(s, d);
    }
    __syncthreads();
    if (t < nb && eh[t]) gbase[t] = atomicAdd(&bcur[t], eh[t]);
    __syncthreads();
    for (int i = t; i < cnt; i += 256) {
        int2 e = sbuf[i];
        int b = e.y >> 9;
        binned[gbase[b] + (i - eoff[b])] = e;
    }
}

__global__ __launch_bounds__(256) void k_csr512(const int2* __restrict__ binned,
                                                const int* __restrict__ bstart,
                                                int* __restrict__ rowstart,
                                                int* __restrict__ col, int N, int E) {
    __shared__ int h[512], cur[512], sc[512];
    int t = threadIdx.x, b = blockIdx.x;
    int es = bstart[b], ee = bstart[b + 1];
    for (int i = t; i < 512; i += 256) h[i] = 0;
    __syncthreads();
    for (int i = es + t; i < ee; i += 256) atomicAdd(&h[binned[i].y & 511], 1);
    __syncthreads();
    for (int i = t; i < 512; i += 256) sc[i] = h[i];
    __syncthreads();
    for (int off = 1; off < 512; off <<= 1) {
        int i0 = t, i1 = t + 256;
        int a0 = (i0 >= off) ? sc[i0 - off] : 0;
        int a1 = (i1 >= off) ? sc[i1 - off] : 0;
        __syncthreads();
        sc[i0] += a0; sc[i1] += a1;
        __syncthreads();
    }
    for (int i = t; i < 512; i += 256) {
        int excl = sc[i] - h[i];
        cur[i] = excl;
        int node = (b << 9) + i;
        if (node < N) rowstart[node] = es + excl;
    }
    __syncthreads();
    for (int i = es + t; i < ee; i += 256) {
        int2 e = binned[i];
        int p = atomicAdd(&cur[e.y & 511], 1);
        col[es + p] = e.x;
    }
    if (b == 0 && t == 0) rowstart[N] = E;
}

// ---------------- CSR gather: A[:,0:128] = sum over in-edges of A[src,128:256] --------
// R17: cross-node chain overlap (two 32-lane half-waves, one node each): 59->56.4us.
// R19: 2-stage software pipeline (8 row-loads in flight, cols a group ahead):
// 56.4 -> <56 us, wall -11. Near the random-access pattern ceiling; done here.

__device__ __forceinline__ void acc8(f32x2 (&acc)[4], u32x4 v) {
#pragma unroll
    for (int d = 0; d < 4; ++d) {
        f32x2 t;
        t.x = __uint_as_float(v[d] << 16);
        t.y = __uint_as_float(v[d] & 0xffff0000u);
        acc[d] += t;
    }
}

__global__ __launch_bounds__(256) void k_gather_bf(const int* __restrict__ rowstart,
                                                   const int* __restrict__ col,
                                                   ushort* __restrict__ A, int N) {
    int t = threadIdx.x;
    int lane = t & 63;
    int node = blockIdx.x * 8 + (t >> 6) * 2 + (lane >> 5);
    int sub = (lane >> 4) & 1; // edge slot within node (0/1)
    int chunk = lane & 15;     // 16B chunk in row
    if (node >= N) return;
    int s = rowstart[node], e = rowstart[node + 1];
    const char* hb = (const char*)A; // row r's h-half at byte r*512 + 256
    unsigned coff = (unsigned)chunk * 16u + 256u;
#define ROWLD(c) (*(const u32x4*)(hb + ((unsigned)(c) * 512u + coff)))
    f32x2 acc[4];
#pragma unroll
    for (int d = 0; d < 4; ++d) acc[d] = (f32x2){0.f, 0.f};
    int i = s + sub;
    if (i + 14 < e) {
        // prologue: rows of G0 and G1 in flight, cols of G2 (if any) in regs
        int c0 = col[i], c1 = col[i + 2], c2 = col[i + 4], c3 = col[i + 6];
        u32x4 a0 = ROWLD(c0), a1 = ROWLD(c1), a2 = ROWLD(c2), a3 = ROWLD(c3);
        c0 = col[i + 8]; c1 = col[i + 10]; c2 = col[i + 12]; c3 = col[i + 14];
        u32x4 b0 = ROWLD(c0), b1 = ROWLD(c1), b2 = ROWLD(c2), b3 = ROWLD(c3);
        i += 16;
        int d0 = 0, d1 = 0, d2 = 0, d3 = 0;
        bool haveC = (i + 6 < e);
        if (haveC) { d0 = col[i]; d1 = col[i + 2]; d2 = col[i + 4]; d3 = col[i + 6]; i += 8; }
        while (true) {
            // phase A: consume a (oldest in queue), refill a from d-cols, then next cols
            acc8(acc, a0); acc8(acc, a1); acc8(acc, a2); acc8(acc, a3);
            if (!haveC) { acc8(acc, b0); acc8(acc, b1); acc8(acc, b2); acc8(acc, b3); break; }
            a0 = ROWLD(d0); a1 = ROWLD(d1); a2 = ROWLD(d2); a3 = ROWLD(d3);
            haveC = (i + 6 < e);
            if (haveC) { d0 = col[i]; d1 = col[i + 2]; d2 = col[i + 4]; d3 = col[i + 6]; i += 8; }
            // phase B: consume b, refill b
            acc8(acc, b0); acc8(acc, b1); acc8(acc, b2); acc8(acc, b3);
            if (!haveC) { acc8(acc, a0); acc8(acc, a1); acc8(acc, a2); acc8(acc, a3); break; }
            b0 = ROWLD(d0); b1 = ROWLD(d1); b2 = ROWLD(d2); b3 = ROWLD(d3);
            haveC = (i + 6 < e);
            if (haveC) { d0 = col[i]; d1 = col[i + 2]; d2 = col[i + 4]; d3 = col[i + 6]; i += 8; }
        }
    }
    // mid tail: full 4-edge groups, 4 in flight
    while (i + 6 < e) {
        int c0 = col[i], c1 = col[i + 2], c2 = col[i + 4], c3 = col[i + 6];
        u32x4 v0 = ROWLD(c0), v1 = ROWLD(c1), v2 = ROWLD(c2), v3 = ROWLD(c3);
        acc8(acc, v0); acc8(acc, v1); acc8(acc, v2); acc8(acc, v3);
        i += 8;
    }
    // singles, 2-deep pipelined
    if (i < e) {
        u32x4 w0 = ROWLD(col[i]);
        for (i += 2; i < e; i += 2) {
            u32x4 w1 = ROWLD(col[i]);
            acc8(acc, w0);
            w0 = w1;
        }
        acc8(acc, w0);
    }
#undef ROWLD
    // reduce the 2 edge slots: lane l <-> l^16 stays within each 32-lane half
#pragma unroll
    for (int d = 0; d < 4; ++d) {
        acc[d].x += __shfl_xor(acc[d].x, 16);
        acc[d].y += __shfl_xor(acc[d].y, 16);
    }
    if (sub == 0) {
        union { ushort u[8]; bf16x8 v; } o;
#pragma unroll
        for (int d = 0; d < 4; ++d) {
            o.u[2 * d] = f2bf(acc[d].x);
            o.u[2 * d + 1] = f2bf(acc[d].y);
        }
        *(bf16x8*)(A + (size_t)node * 256 + chunk * 8) = o.v;
    }
}

// ---------------- fused GRU GEMM (K=256 over [s|h]); h state bf16-only --------------
// R8/R18: the 128-reg accumulator set spills to scratch at ANY min-waves > 2.
// Pinned at min-waves 2, full 64x512 per-block tile. Do not touch occupancy.
// R20: (a) skip structural-zero MFMAs — n-gate blocks are half-zero by
// construction (g=2 zero for ks>=4, g=3 zero for ks<4): 256->192 MFMA/wave and
// -25% B L2 traffic, bitwise-identical results. (b) epilogue divisions were
// IEEE div_scale/fmas/fixup chains (~8 VALU each, 3 per output — the bulk of
// VALUBusy 46%); replaced with v_rcp_f32 (1 ulp, invisible under bf16 rounding).

#define LDA 264
__global__ __launch_bounds__(256, 2) void k_gru_mfma(
    const ushort* __restrict__ A, const ushort* __restrict__ Bc2,
    const float* __restrict__ bias, ushort* __restrict__ Ah) {
    __shared__ ushort As[64 * LDA];
    int t = threadIdx.x;
    int rowb = blockIdx.x << 6;
    for (int c = t; c < 2048; c += 256) {
        int r = c >> 5, off = (c & 31) * 8;
        *(bf16x8*)(As + r * LDA + off) =
            *(const bf16x8*)(A + (size_t)(rowb + r) * 256 + off);
    }
    __syncthreads();
    int w = t >> 6, lane = t & 63;
    int quad = lane >> 4, tn = lane & 15;
    f32x4 acc[4][4][2];
#pragma unroll
    for (int rt = 0; rt < 4; ++rt)
#pragma unroll
        for (int g = 0; g < 4; ++g)
#pragma unroll
            for (int c2 = 0; c2 < 2; ++c2) acc[rt][g][c2] = (f32x4){0.f, 0.f, 0.f, 0.f};
    // ks 0..3: K-half from s — gates r,z,i_n (g=0,1,2); g=3 rows are zero here
    for (int ks = 0; ks < 4; ++ks) {
        int k0 = ks * 32 + quad * 8;
        bf16x8 bfr[3][2];
#pragma unroll
        for (int j = 0; j < 3; ++j)
#pragma unroll
            for (int c2 = 0; c2 < 2; ++c2) {
                int ct = j * 8 + w * 2 + c2;
                bfr[j][c2] = *(const bf16x8*)(Bc2 + (size_t)((ct * 8 + ks) * 64 + lane) * 8);
            }
        bf16x8 af[4];
#pragma unroll
        for (int rt = 0; rt < 4; ++rt)
            af[rt] = *(const bf16x8*)(As + (rt * 16 + tn) * LDA + k0);
#pragma unroll
        for (int rt = 0; rt < 4; ++rt)
#pragma unroll
            for (int j = 0; j < 3; ++j)
#pragma unroll
                for (int c2 = 0; c2 < 2; ++c2)
                    acc[rt][j][c2] = __builtin_amdgcn_mfma_f32_16x16x32_bf16(
                        af[rt], bfr[j][c2], acc[rt][j][c2], 0, 0, 0);
    }
    // ks 4..7: K-half from h — gates r,z,h_n (g=0,1,3); g=2 rows are zero here
    for (int ks = 4; ks < 8; ++ks) {
        int k0 = ks * 32 + quad * 8;
        bf16x8 bfr[3][2];
#pragma unroll
        for (int j = 0; j < 3; ++j)
#pragma unroll
            for (int c2 = 0; c2 < 2; ++c2) {
                int g = (j == 2) ? 3 : j;
                int ct = g * 8 + w * 2 + c2;
                bfr[j][c2] = *(const bf16x8*)(Bc2 + (size_t)((ct * 8 + ks) * 64 + lane) * 8);
            }
        bf16x8 af[4];
#pragma unroll
        for (int rt = 0; rt < 4; ++rt)
            af[rt] = *(const bf16x8*)(As + (rt * 16 + tn) * LDA + k0);
#pragma unroll
        for (int rt = 0; rt < 4; ++rt)
#pragma unroll
            for (int j = 0; j < 3; ++j)
#pragma unroll
                for (int c2 = 0; c2 < 2; ++c2) {
                    int g = (j == 2) ? 3 : j;
                    acc[rt][g][c2] = __builtin_amdgcn_mfma_f32_16x16x32_bf16(
                        af[rt], bfr[j][c2], acc[rt][g][c2], 0, 0, 0);
                }
    }
#pragma unroll
    for (int c2 = 0; c2 < 2; ++c2) {
        int cc = w * 32 + c2 * 16 + tn;
        float br = bias[cc], bz = bias[128 + cc], bin = bias[256 + cc], bhn = bias[384 + cc];
#pragma unroll
        for (int rt = 0; rt < 4; ++rt)
#pragma unroll
            for (int r = 0; r < 4; ++r) {
                int rl = rt * 16 + quad * 4 + r;
                int row = rowb + rl;
                float ur = acc[rt][0][c2][r] + br;
                float uz = acc[rt][1][c2][r] + bz;
                float xin = acc[rt][2][c2][r] + bin;
                float xhn = acc[rt][3][c2][r] + bhn;
                float rr = __builtin_amdgcn_rcpf(1.f + __expf(-ur));
                float zz = __builtin_amdgcn_rcpf(1.f + __expf(-uz));
                float xt = xin + rr * xhn;
                float ex = __expf(2.f * fminf(fmaxf(xt, -15.f), 15.f));
                float nn = (ex - 1.f) * __builtin_amdgcn_rcpf(ex + 1.f);
                float ho = bf2f(As[rl * LDA + 128 + cc]);
                float hv = (1.f - zz) * nn + zz * ho;
                Ah[(size_t)row * 256 + cc] = f2bf(hv);
            }
    }
}

// ---------------- MFMA GEMM (fc1) with fused BN-stats ----------

#define LDA2 136
__global__ __launch_bounds__(256, 2) void k_mm_mfma(
    const ushort* __restrict__ Ain, int astride, const ushort* __restrict__ B2,
    ushort* __restrict__ mo, float* __restrict__ statsl, int N) {
    __shared__ ushort As[64 * LDA2];
    int t = threadIdx.x;
    int rowb = blockIdx.x << 6;
    for (int c = t; c < 1024; c += 256) {
        int r = c >> 4, off = (c & 15) * 8;
        *(bf16x8*)(As + r * LDA2 + off) =
            *(const bf16x8*)(Ain + (size_t)(rowb + r) * astride + off);
    }
    __syncthreads();
    int w = t >> 6, lane = t & 63;
    int quad = lane >> 4, tn = lane & 15;
    f32x4 acc[4][2];
#pragma unroll
    for (int rt = 0; rt < 4; ++rt)
#pragma unroll
        for (int c2 = 0; c2 < 2; ++c2) acc[rt][c2] = (f32x4){0.f, 0.f, 0.f, 0.f};
    for (int ks = 0; ks < 4; ++ks) {
        int k0 = ks * 32 + quad * 8;
        bf16x8 bfr[2];
#pragma unroll
        for (int c2 = 0; c2 < 2; ++c2) {
            int ct = w * 2 + c2;
            bfr[c2] = *(const bf16x8*)(B2 + (size_t)((ct * 4 + ks) * 64 + lane) * 8);
        }
        bf16x8 af[4];
#pragma unroll
        for (int rt = 0; rt < 4; ++rt)
            af[rt] = *(const bf16x8*)(As + (rt * 16 + tn) * LDA2 + k0);
#pragma unroll
        for (int rt = 0; rt < 4; ++rt)
#pragma unroll
            for (int c2 = 0; c2 < 2; ++c2)
                acc[rt][c2] = __builtin_amdgcn_mfma_f32_16x16x32_bf16(
                    af[rt], bfr[c2], acc[rt][c2], 0, 0, 0);
    }
#pragma unroll
    for (int c2 = 0; c2 < 2; ++c2) {
        int col = w * 32 + c2 * 16 + tn;
        float s = 0.f, s2 = 0.f;
#pragma unroll
        for (int rt = 0; rt < 4; ++rt)
#pragma unroll
            for (int r = 0; r < 4; ++r) {
                int row = rowb + rt * 16 + quad * 4 + r;
                float v = acc[rt][c2][r];
                mo[row * 128 + col] = f2bf(v);
                if (row < N) { s += v; s2 += v * v; }
            }
        s += __shfl_xor(s, 16);
        s += __shfl_xor(s, 32);
        s2 += __shfl_xor(s2, 16);
        s2 += __shfl_xor(s2, 32);
        if (quad == 0) {
            int slice = blockIdx.x & 63;
            atomicAdd(&statsl[(slice * 2 + 0) * 128 + col], s);
            atomicAdd(&statsl[(slice * 2 + 1) * 128 + col], s2);
        }
    }
}

// ---------------- BN finalize / pool / head ----------------

__global__ void k_bnfinal(const float* __restrict__ statsl, float* __restrict__ stats,
                          const float* __restrict__ gamma,
                          const float* __restrict__ beta, float n) {
    int j = threadIdx.x;
    if (j < HID) {
        float s = 0.f, s2 = 0.f;
        for (int sl = 0; sl < 64; ++sl) {
            s += statsl[(sl * 2 + 0) * 128 + j];
            s2 += statsl[(sl * 2 + 1) * 128 + j];
        }
        float mu = s / n;
        float var = s2 / n - mu * mu;
        float sc = gamma[j] * rsqrtf(var + BN_EPS);
        stats[256 + j] = sc;
        stats[384 + j] = beta[j] - mu * sc;
    }
}

// atomic-light pool: block = (graph, quarter), rows contiguous via gstart
__global__ __launch_bounds__(256) void k_pool(const ushort* __restrict__ y,
                                              const float* __restrict__ stats,
                                              const int* __restrict__ gstart,
                                              float* __restrict__ gsum) {
    int g = blockIdx.x >> 2, q = blockIdx.x & 3;
    int f = threadIdx.x & 127, half = threadIdx.x >> 7;
    int gs = gstart[g], ge = gstart[g + 1];
    int len = ge - gs;
    int r0 = gs + ((len * q) >> 2), r1 = gs + ((len * (q + 1)) >> 2);
    float sc = stats[256 + f], sh = stats[384 + f];
    float acc = 0.f;
    for (int n = r0 + half; n < r1; n += 2)
        acc += fmaxf(bf2f(y[n * HID + f]) * sc + sh, 0.f);
    __shared__ float ls[2][HID];
    ls[half][f] = acc;
    __syncthreads();
    if (half == 0) atomicAdd(&gsum[g * HID + f], ls[0][f] + ls[1][f]);
}

__global__ void k_head(const float* __restrict__ gsum, const int* __restrict__ gstart,
                       const float* __restrict__ w2, const float* __restrict__ b2,
                       float* __restrict__ out) {
    int g = blockIdx.x * blockDim.x + threadIdx.x;
    if (g >= NGRAPHS) return;
    float cnt = (float)(gstart[g + 1] - gstart[g]);
    float inv = 1.0f / fmaxf(cnt, 1.0f);
    float logits[NCLASSES];
    float mx = -1e30f;
    for (int c = 0; c < NCLASSES; ++c) {
        float acc = b2[c];
        for (int f = 0; f < HID; ++f) acc += gsum[g * HID + f] * inv * w2[c * HID + f];
        logits[c] = acc;
        mx = fmaxf(mx, acc);
    }
    float se = 0.f;
    for (int c = 0; c < NCLASSES; ++c) se += expf(logits[c] - mx);
    float lse = mx + logf(se);
    for (int c = 0; c < NCLASSES; ++c) out[g * NCLASSES + c] = logits[c] - lse;
}

// ---------------- launch ----------------

extern "C" void kernel_launch(void* const* d_in, const int* in_sizes, int n_in,
                              void* d_out, int out_size, void* d_ws, size_t ws_size,
                              hipStream_t stream) {
    const float* x     = (const float*)d_in[0];
    const int*   ei    = (const int*)d_in[1];
    const int*   batch = (const int*)d_in[2];
    const float* ggnnw = (const float*)d_in[3];
    const float* w_ih  = (const float*)d_in[4];
    const float* w_hh  = (const float*)d_in[5];
    const float* b_ih  = (const float*)d_in[6];
    const float* b_hh  = (const float*)d_in[7];
    const float* fc1_w = (const float*)d_in[8];
    // d_in[9] fc1_b: cancels exactly in training-mode BN -> unused
    const float* gamma = (const float*)d_in[10];
    const float* beta  = (const float*)d_in[11];
    const float* fc2_w = (const float*)d_in[12];
    const float* fc2_b = (const float*)d_in[13];
    float* out = (float*)d_out;

    const int N = in_sizes[0] / HID; // 100000
    const int E = in_sizes[1] / 2;   // 1600000
    const int nblk64 = (N + 63) / 64;
    const int P = nblk64 * 64;
    const int nbuck = (N + 511) >> 9; // 196

    char* w = (char*)d_ws;
    auto alloc = [&](size_t bytes) -> char* {
        char* p = w;
        w += (bytes + 255) & ~(size_t)255;
        return p;
    };
    ushort* A   = (ushort*)alloc(sizeof(ushort) * (size_t)P * 256); // [s | h] bf16
    ushort* y   = (ushort*)alloc(sizeof(ushort) * (size_t)P * HID); // fc1 output
    int2*   binned = (int2*)y; // alias: binned dead before k_mm writes y
    ushort* Bc2 = (ushort*)alloc(sizeof(ushort) * NLAYERS * 512 * 256);
    float*  C   = (float*)alloc(sizeof(float) * NLAYERS * 128 * 384);
    ushort* f1b = (ushort*)alloc(sizeof(ushort) * HID * HID);
    float*  bias = (float*)alloc(sizeof(float) * 512);
    int* rowstart = (int*)alloc(sizeof(int) * (N + 4));
    int* colb     = (int*)alloc(sizeof(int) * E);
    int* bstart   = (int*)alloc(sizeof(int) * (nbuck + 4));
    int* bcur     = (int*)alloc(sizeof(int) * (nbuck + 4));
    int* gstart   = (int*)alloc(sizeof(int) * (NGRAPHS + 4));
    // zero-initialized region: bhist, statsl (64 slices x 2 x 128), stats, gsum
    size_t zelems = (size_t)nbuck + 64 * 2 * 128 + 512 + NGRAPHS * HID;
    char* zbase = alloc(zelems * 4);
    int*   bhist  = (int*)zbase;
    float* statsl = (float*)(bhist + nbuck);
    float* stats  = statsl + 64 * 2 * 128;
    float* gsum   = stats + 512;

    hipMemsetAsync(zbase, 0, zelems * 4, stream);

    k_init_x<<<(N * HID + 255) / 256, 256, 0, stream>>>(x, A, N);
    k_wgemm<<<NLAYERS * 128, 128, 0, stream>>>(ggnnw, w_ih, b_ih, b_hh, C, bias);
    k_build_Bc<<<(NLAYERS * 512 * 256 + 255) / 256, 256, 0, stream>>>(C, w_hh, Bc2);
    k_cvt_fc1<<<(16384 + 255) / 256, 256, 0, stream>>>(fc1_w, f1b);

    // staged CSR build (+ gstart fused into bhist dispatch)
    int nchunk = (E + CHUNK - 1) / CHUNK;
    int ngblk = (N + 256) / 256;
    k_bhist<<<nchunk + ngblk, 256, 0, stream>>>(ei, E, nbuck, bhist, batch, gstart, N,
                                                nchunk);
    k_bscan<<<1, 256, 0, stream>>>(bhist, nbuck, bstart, bcur, E);
    k_binfill<<<nchunk, 256, 0, stream>>>(ei, E, nbuck, bcur, binned);
    k_csr512<<<nbuck, 256, 0, stream>>>(binned, bstart, rowstart, colb, N, E);

    for (int l = 0; l < NLAYERS; ++l) {
        k_gather_bf<<<(N + 7) / 8, 256, 0, stream>>>(rowstart, colb, A, N);
        k_gru_mfma<<<nblk64, 256, 0, stream>>>(A, Bc2 + (size_t)l * 512 * 256,
                                               bias, A + 128);
    }

    // head: fc1 (+fused BN stats) -> BN finalize -> pool -> fc2 -> log_softmax
    k_mm_mfma<<<nblk64, 256, 0, stream>>>(A + 128, 256, f1b, y, statsl, N);
    k_bnfinal<<<1, 128, 0, stream>>>(statsl, stats, gamma, beta, (float)N);
    k_pool<<<NGRAPHS * 4, 256, 0, stream>>>(y, stats, gstart, gsum);
    k_head<<<1, 256, 0, stream>>>(gsum, gstart, fc2_w, fc2_b, out);
}